// Round 3
// baseline (526.918 us; speedup 1.0000x reference)
//
#include <hip/hip_runtime.h>
#include <cstdint>
#include <cstddef>

#define Ndim 8
#define Odim 32
#define Cdim 16
#define Hdim 512
#define Rdim 8
#define TW 64
#define TH 4
#define NBW (Hdim/TW)   // 8  w-blocks
#define NBH (Hdim/TH)   // 128 h-blocks

typedef _Float16 half2_t __attribute__((ext_vector_type(2)));

union U16 { uint4 u; half2_t h[4]; _Float16 f[8]; };

__device__ __forceinline__ half2_t pk(float a, float b) {
    half2_t h; h[0] = (_Float16)a; h[1] = (_Float16)b; return h;
}

#if defined(__has_builtin)
#if __has_builtin(__builtin_amdgcn_fdot2)
#define HAVE_FDOT2 1
#endif
#endif

__device__ __forceinline__ float fdot2f(half2_t a, half2_t b, float acc) {
#ifdef HAVE_FDOT2
    return __builtin_amdgcn_fdot2(a, b, acc, false);
#else
    return acc + (float)a[0] * (float)b[0] + (float)a[1] * (float)b[1];
#endif
}

// DPP ladder full-wave64 sum; valid in lane 63 (and 47..63).
template<int CTRL>
__device__ __forceinline__ float dppadd(float v) {
    return v + __int_as_float(__builtin_amdgcn_update_dpp(
        0, __float_as_int(v), CTRL, 0xf, 0xf, true));
}
__device__ __forceinline__ float wave_sum63(float v) {
    v = dppadd<0xB1>(v);    // xor1
    v = dppadd<0x4E>(v);    // xor2
    v = dppadd<0x141>(v);   // row_half_mirror
    v = dppadd<0x140>(v);   // row_mirror
    v = dppadd<0x142>(v);   // row_bcast15
    v = dppadd<0x143>(v);   // row_bcast31
    return v;
}

// Pre-pack L into f16: lsig = L*coupling (h-side), lraw = L (w-side).
__global__ __launch_bounds__(256)
void sylo_prep(const float* __restrict__ L, const float* __restrict__ coup,
               uint4* __restrict__ lsig, uint4* __restrict__ lraw)
{
    int row = blockIdx.x * 256 + threadIdx.x;      // (o*C + c)*H + h, < 262144
    int oc = row >> 9;
    const float4* lp = (const float4*)(L + (size_t)row * Rdim);
    const float4* cp = (const float4*)(coup + (size_t)oc * Rdim);
    float4 l0 = lp[0], l1 = lp[1];
    float4 c0 = cp[0], c1 = cp[1];
    U16 s, r;
    s.h[0] = pk(l0.x * c0.x, l0.y * c0.y); s.h[1] = pk(l0.z * c0.z, l0.w * c0.w);
    s.h[2] = pk(l1.x * c1.x, l1.y * c1.y); s.h[3] = pk(l1.z * c1.z, l1.w * c1.w);
    r.h[0] = pk(l0.x, l0.y); r.h[1] = pk(l0.z, l0.w);
    r.h[2] = pk(l1.x, l1.y); r.h[3] = pk(l1.z, l1.w);
    lsig[row] = s.u;
    lraw[row] = r.u;
}

// MODE 0: deterministic partial-sum buffers + reduce kernel, prepped f16 L.
// MODE 1: atomicAdd into rs/cs, prepped f16 L (smaller ws).
// MODE 2: atomicAdd, convert L from fp32 inline (minimal ws).
template<int PASS, int MODE>
__global__ __launch_bounds__(256, 4)
void sylo_main(const float* __restrict__ Xg, const float* __restrict__ Lg,
               const float* __restrict__ coupg, const float* __restrict__ biasg,
               const uint4* __restrict__ lsig, const uint4* __restrict__ lraw,
               float* __restrict__ outg,
               float* __restrict__ rsp, float* __restrict__ csp,
               float* __restrict__ rs, float* __restrict__ cs)
{
    const int tid = threadIdx.x;
    const int j = tid & 63, iw = tid >> 6;         // wave iw owns row h0+iw, lane j owns col
    const int bw = blockIdx.x, bh = blockIdx.y;
    const int w0 = bw * TW, h0 = bh * TH;
    const int hh = h0 + iw;
    const int ww = w0 + j;
    const size_t S = (size_t)Ndim * Odim * Hdim;

    __shared__ __align__(16) _Float16 lw[Cdim][TW][Rdim];  // 16 KB
    __shared__ float csl[TH][Ndim][TW];                    // 8 KB

    // ---- X prologue: one pixel, all (c,n), f16 c-pairs in regs (64 VGPR) ----
    half2_t xa[64];
    {
        const size_t HH = (size_t)Hdim * Hdim;
        const size_t q = (size_t)hh * Hdim + ww;
        #pragma unroll
        for (int c = 0; c < Cdim; c += 2) {
            #pragma unroll
            for (int n = 0; n < Ndim; ++n)
                xa[(c >> 1) * 8 + n] = pk(Xg[(size_t)(n * Cdim + c) * HH + q],
                                          Xg[(size_t)(n * Cdim + c + 1) * HH + q]);
        }
    }

    const int ruh = __builtin_amdgcn_readfirstlane(hh);   // wave-uniform row -> s_load path

    // staging prefetch for o=0 (MODE<2): 4 uint4/thread
    uint4 g[4];
    if (MODE < 2) {
        #pragma unroll
        for (int k = 0; k < 4; ++k) {
            int e = tid + k * 256, c = e >> 6, w = e & 63;
            g[k] = lraw[(size_t)(0 * Cdim + c) * Hdim + w0 + w];
        }
    }

    for (int o = 0; o < Odim; ++o) {
        __syncthreads();   // lw + csl free (previous o fully consumed)

        if (MODE < 2) {
            #pragma unroll
            for (int k = 0; k < 4; ++k) {
                int e = tid + k * 256, c = e >> 6, w = e & 63;
                *(uint4*)&lw[c][w][0] = g[k];
            }
            if (o + 1 < Odim) {   // prefetch next-o tile; rides under compute
                #pragma unroll
                for (int k = 0; k < 4; ++k) {
                    int e = tid + k * 256, c = e >> 6, w = e & 63;
                    g[k] = lraw[(size_t)((o + 1) * Cdim + c) * Hdim + w0 + w];
                }
            }
        } else {
            #pragma unroll
            for (int k = 0; k < 4; ++k) {
                int e = tid + k * 256, c = e >> 6, w = e & 63;
                const float4* gp = (const float4*)(Lg + ((size_t)(o * Cdim + c) * Hdim + w0 + w) * Rdim);
                float4 l0 = gp[0], l1 = gp[1];
                U16 t;
                t.h[0] = pk(l0.x, l0.y); t.h[1] = pk(l0.z, l0.w);
                t.h[2] = pk(l1.x, l1.y); t.h[3] = pk(l1.z, l1.w);
                *(uint4*)&lw[c][w][0] = t.u;
            }
        }
        __syncthreads();   // lw ready

        // ---- T per c (A: wave-uniform scalar loads; B: LDS), pack to f16 pairs ----
        float p[Ndim];
        #pragma unroll
        for (int n = 0; n < Ndim; ++n) p[n] = 0.f;

        half2_t t2[8];
        float tprev = 0.f;
        #pragma unroll
        for (int c = 0; c < Cdim; ++c) {
            U16 A, B;
            if (MODE < 2) {
                A.u = lsig[(size_t)(o * Cdim + c) * Hdim + ruh];
            } else {
                const float4* a0 = (const float4*)(Lg + ((size_t)(o * Cdim + c) * Hdim + ruh) * Rdim);
                const float4* cpp = (const float4*)(coupg + (size_t)(o * Cdim + c) * Rdim);
                float4 l0 = a0[0], l1 = a0[1];
                float4 c0 = cpp[0], c1 = cpp[1];
                A.h[0] = pk(l0.x * c0.x, l0.y * c0.y); A.h[1] = pk(l0.z * c0.z, l0.w * c0.w);
                A.h[2] = pk(l1.x * c1.x, l1.y * c1.y); A.h[3] = pk(l1.z * c1.z, l1.w * c1.w);
            }
            B.u = *(const uint4*)&lw[c][j][0];
            float t = 0.f;
            #pragma unroll
            for (int r = 0; r < 4; ++r) t = fdot2f(A.h[r], B.h[r], t);
            if (c & 1) t2[c >> 1] = pk(tprev, t);
            else       tprev = t;
        }

        // ---- P over (c,n) ----
        #pragma unroll
        for (int cp8 = 0; cp8 < 8; ++cp8) {
            #pragma unroll
            for (int n = 0; n < Ndim; ++n)
                p[n] = fdot2f(t2[cp8], xa[cp8 * 8 + n], p[n]);
        }

        if (PASS == 0) {
            #pragma unroll
            for (int n = 0; n < Ndim; ++n) {
                float r = wave_sum63(p[n]);          // row sum on VALU (DPP)
                if (j == 63) {
                    size_t i0 = (size_t)(n * Odim + o) * Hdim + hh;
                    if (MODE == 0) rsp[(size_t)bw * S + i0] = r;
                    else atomicAdd(&rs[i0], r);
                }
                csl[iw][n][j] = p[n];
            }
            __syncthreads();   // csl ready
            #pragma unroll
            for (int k = 0; k < 2; ++k) {
                int e = tid + k * 256;
                int n = e >> 6, jj = e & 63;
                float v = csl[0][n][jj] + csl[1][n][jj] + csl[2][n][jj] + csl[3][n][jj];
                size_t idx = (size_t)(n * Odim + o) * Hdim + w0 + jj;
                if (MODE == 0) csp[(size_t)bh * S + idx] = v;
                else atomicAdd(&cs[idx], v);
            }
            // loop-top barrier protects csl/lw reuse
        } else {
            float bb = biasg[o];
            #pragma unroll
            for (int n = 0; n < Ndim; ++n) {
                size_t i0 = (size_t)(n * Odim + o) * Hdim;
                float rv = rs[i0 + ruh];             // wave-uniform -> s_load
                float cv = cs[i0 + ww];              // coalesced vector load
                float v = rv + cv - p[n] + bb;
                if (hh == ww) v = 0.f;
                outg[(i0 + hh) * Hdim + ww] = v;     // coalesced store
            }
        }
    }
}

__global__ __launch_bounds__(256)
void sylo_reduce(const float* __restrict__ rsp, const float* __restrict__ csp,
                 float* __restrict__ rs, float* __restrict__ cs)
{
    int t = blockIdx.x * 256 + threadIdx.x;   // < 131072
    const size_t S = (size_t)Ndim * Odim * Hdim;
    float a = 0.f;
    #pragma unroll
    for (int k = 0; k < NBW; ++k) a += rsp[(size_t)k * S + t];
    rs[t] = a;
    float b = 0.f;
    #pragma unroll 16
    for (int k = 0; k < NBH; ++k) b += csp[(size_t)k * S + t];
    cs[t] = b;
}

extern "C" void kernel_launch(void* const* d_in, const int* in_sizes, int n_in,
                              void* d_out, int out_size, void* d_ws, size_t ws_size,
                              hipStream_t stream)
{
    const float* X    = (const float*)d_in[0];
    const float* L    = (const float*)d_in[1];
    const float* bias = (const float*)d_in[2];
    const float* coup = (const float*)d_in[3];
    float* out = (float*)d_out;

    const size_t S    = (size_t)Ndim * Odim * Hdim;    // 131072
    const size_t NL16 = (size_t)Odim * Cdim * Hdim;    // 262144 rows of 16B
    const size_t need0 = NL16 * 16 * 2 + (NBW + NBH + 2) * S * 4;  // ~81 MB
    const size_t need1 = NL16 * 16 * 2 + 2 * S * 4;                // ~9.4 MB
    dim3 grid(NBW, NBH), blk(256);

    if (ws_size >= need0) {
        uint4* lsig = (uint4*)d_ws;
        uint4* lraw = lsig + NL16;
        float* rsp = (float*)(lraw + NL16);
        float* csp = rsp + (size_t)NBW * S;
        float* rs  = csp + (size_t)NBH * S;
        float* cs  = rs + S;
        sylo_prep<<<dim3(1024), blk, 0, stream>>>(L, coup, lsig, lraw);
        sylo_main<0,0><<<grid, blk, 0, stream>>>(X, L, coup, bias, lsig, lraw, out, rsp, csp, rs, cs);
        sylo_reduce<<<dim3(512), blk, 0, stream>>>(rsp, csp, rs, cs);
        sylo_main<1,0><<<grid, blk, 0, stream>>>(X, L, coup, bias, lsig, lraw, out, rsp, csp, rs, cs);
    } else if (ws_size >= need1) {
        uint4* lsig = (uint4*)d_ws;
        uint4* lraw = lsig + NL16;
        float* rs = (float*)(lraw + NL16);
        float* cs = rs + S;
        hipMemsetAsync(rs, 0, 2 * S * sizeof(float), stream);
        sylo_prep<<<dim3(1024), blk, 0, stream>>>(L, coup, lsig, lraw);
        sylo_main<0,1><<<grid, blk, 0, stream>>>(X, L, coup, bias, lsig, lraw, out, nullptr, nullptr, rs, cs);
        sylo_main<1,1><<<grid, blk, 0, stream>>>(X, L, coup, bias, lsig, lraw, out, nullptr, nullptr, rs, cs);
    } else {
        float* rs = (float*)d_ws;
        float* cs = rs + S;
        hipMemsetAsync(rs, 0, 2 * S * sizeof(float), stream);
        sylo_main<0,2><<<grid, blk, 0, stream>>>(X, L, coup, bias, nullptr, nullptr, out, nullptr, nullptr, rs, cs);
        sylo_main<1,2><<<grid, blk, 0, stream>>>(X, L, coup, bias, nullptr, nullptr, out, nullptr, nullptr, rs, cs);
    }
}

// Round 4
// 285.662 us; speedup vs baseline: 1.8445x; 1.8445x over previous
//
#include <hip/hip_runtime.h>
#include <cstdint>
#include <cstddef>

#define Ndim 8
#define Odim 32
#define Cdim 16
#define Hdim 512
#define Rdim 8
#define TW 64
#define TH 4
#define NBW (Hdim/TW)   // 8   w-blocks
#define NBH (Hdim/TH)   // 128 h-blocks

typedef _Float16 half2_t __attribute__((ext_vector_type(2)));

union U16 { uint4 u; half2_t h[4]; _Float16 f[8]; };

__device__ __forceinline__ half2_t pk(float a, float b) {
    half2_t h; h[0] = (_Float16)a; h[1] = (_Float16)b; return h;
}

#if defined(__has_builtin)
#if __has_builtin(__builtin_amdgcn_fdot2)
#define HAVE_FDOT2 1
#endif
#endif

__device__ __forceinline__ float fdot2f(half2_t a, half2_t b, float acc) {
#ifdef HAVE_FDOT2
    return __builtin_amdgcn_fdot2(a, b, acc, false);
#else
    return acc + (float)a[0] * (float)b[0] + (float)a[1] * (float)b[1];
#endif
}

// async global(16B/lane) -> LDS (wave-uniform base + lane*16), gfx950
__device__ __forceinline__ void stage16(const uint4* g, uint4* l) {
    __builtin_amdgcn_global_load_lds(
        (const __attribute__((address_space(1))) uint32_t*)g,
        (__attribute__((address_space(3))) uint32_t*)l, 16, 0, 0);
}

// DPP ladder full-wave64 sum; valid in lane 63.
template<int CTRL>
__device__ __forceinline__ float dppadd(float v) {
    return v + __int_as_float(__builtin_amdgcn_update_dpp(
        0, __float_as_int(v), CTRL, 0xf, 0xf, true));
}
__device__ __forceinline__ float wave_sum63(float v) {
    v = dppadd<0xB1>(v);
    v = dppadd<0x4E>(v);
    v = dppadd<0x141>(v);
    v = dppadd<0x140>(v);
    v = dppadd<0x142>(v);
    v = dppadd<0x143>(v);
    return v;
}

// Pre-pack L to f16.
//   lsigT[(o*H + h)*C + c] = (L*coupling)[o,c,h,:]   (A-side, contiguous in c for s_load)
//   lraw [(o*C + c)*H + w] = L[o,c,w,:]              (B-side, contiguous in w for staging)
__global__ __launch_bounds__(256)
void sylo_prep(const float* __restrict__ L, const float* __restrict__ coup,
               uint4* __restrict__ lsigT, uint4* __restrict__ lraw)
{
    int row = blockIdx.x * 256 + threadIdx.x;      // (o*C + c)*H + h, < 262144
    int oc = row >> 9, h = row & 511;
    int o = oc >> 4, c = oc & 15;
    const float4* lp = (const float4*)(L + (size_t)row * Rdim);
    const float4* cp = (const float4*)(coup + (size_t)oc * Rdim);
    float4 l0 = lp[0], l1 = lp[1];
    float4 c0 = cp[0], c1 = cp[1];
    U16 s, r;
    s.h[0] = pk(l0.x * c0.x, l0.y * c0.y); s.h[1] = pk(l0.z * c0.z, l0.w * c0.w);
    s.h[2] = pk(l1.x * c1.x, l1.y * c1.y); s.h[3] = pk(l1.z * c1.z, l1.w * c1.w);
    r.h[0] = pk(l0.x, l0.y); r.h[1] = pk(l0.z, l0.w);
    r.h[2] = pk(l1.x, l1.y); r.h[3] = pk(l1.z, l1.w);
    lsigT[((size_t)o * Hdim + h) * Cdim + c] = s.u;
    lraw[row] = r.u;
}

// MODE 0: deterministic partial sums + reduce kernel (prepped f16 L, async staging).
// MODE 1: atomicAdd into rs/cs (prepped f16 L, async staging).
// MODE 2: atomicAdd, raw fp32 L converted inline, reg staging (minimal ws).
template<int PASS, int MODE>
__global__ __launch_bounds__(256, 4)
void sylo_main(const float* __restrict__ Xg, const float* __restrict__ Lg,
               const float* __restrict__ coupg, const float* __restrict__ biasg,
               const uint4* __restrict__ lsigT, const uint4* __restrict__ lraw,
               float* __restrict__ outg,
               float* __restrict__ rsp, float* __restrict__ csp,
               float* __restrict__ rs, float* __restrict__ cs)
{
    const int tid = threadIdx.x;
    const int j = tid & 63, iw = tid >> 6;         // wave iw owns row h0+iw; lane j owns col
    const int bw = blockIdx.x, bh = blockIdx.y;
    const int w0 = bw * TW, h0 = bh * TH;
    const int hh = h0 + iw;
    const int ww = w0 + j;
    const size_t S = (size_t)Ndim * Odim * Hdim;

    __shared__ __align__(16) uint4 lw[2][Cdim][TW];   // 32 KB double-buffered B tiles
    __shared__ float csl[TH][Ndim][TW];               // 8 KB col partials

    // ---- X prologue: one pixel, all (c,n), f16 c-pairs in regs (64 VGPR) ----
    half2_t xa[64];
    {
        const size_t HH = (size_t)Hdim * Hdim;
        const size_t q = (size_t)hh * Hdim + ww;
        #pragma unroll
        for (int c = 0; c < Cdim; c += 2) {
            #pragma unroll
            for (int n = 0; n < Ndim; ++n)
                xa[(c >> 1) * 8 + n] = pk(Xg[(size_t)(n * Cdim + c) * HH + q],
                                          Xg[(size_t)(n * Cdim + c + 1) * HH + q]);
        }
    }

    const int ruh = __builtin_amdgcn_readfirstlane(hh);  // wave-uniform row

    // prologue stage: buffer 0 <- o=0 (each wave stages its 4 c-rows)
    if (MODE < 2) {
        #pragma unroll
        for (int k = 0; k < 4; ++k) {
            int c = iw * 4 + k;
            stage16(lraw + ((size_t)c * Hdim + w0 + j), &lw[0][c][0]);
        }
    }

    for (int o = 0; o < Odim; ++o) {
        const int cur = o & 1;
        __syncthreads();   // drains staging vmcnt; protects lw/csl reuse

        if (MODE < 2) {
            if (o + 1 < Odim) {   // async stage next-o tile; lands before next barrier
                #pragma unroll
                for (int k = 0; k < 4; ++k) {
                    int c = iw * 4 + k;
                    stage16(lraw + ((size_t)((o + 1) * Cdim + c) * Hdim + w0 + j),
                            &lw[cur ^ 1][c][0]);
                }
            }
        } else {
            #pragma unroll
            for (int k = 0; k < 4; ++k) {
                int e = tid + k * 256, c = e >> 6, w = e & 63;
                const float4* gp = (const float4*)(Lg + ((size_t)(o * Cdim + c) * Hdim + w0 + w) * Rdim);
                float4 l0 = gp[0], l1 = gp[1];
                U16 t;
                t.h[0] = pk(l0.x, l0.y); t.h[1] = pk(l0.z, l0.w);
                t.h[2] = pk(l1.x, l1.y); t.h[3] = pk(l1.z, l1.w);
                lw[0][c][w] = t.u;
            }
            __syncthreads();
        }

        // ---- T per c: A uniform (SGPR s_load), B per-lane from LDS ----
        half2_t t2[8];
        float tprev = 0.f;
        #pragma unroll
        for (int c = 0; c < Cdim; ++c) {
            U16 A, B;
            if (MODE < 2) {
                A.u = lsigT[((size_t)o * Hdim + ruh) * Cdim + c];
            } else {
                const float4* a0 = (const float4*)(Lg + ((size_t)(o * Cdim + c) * Hdim + ruh) * Rdim);
                const float4* cpp = (const float4*)(coupg + (size_t)(o * Cdim + c) * Rdim);
                float4 l0 = a0[0], l1 = a0[1];
                float4 c0 = cpp[0], c1 = cpp[1];
                A.h[0] = pk(l0.x * c0.x, l0.y * c0.y); A.h[1] = pk(l0.z * c0.z, l0.w * c0.w);
                A.h[2] = pk(l1.x * c1.x, l1.y * c1.y); A.h[3] = pk(l1.z * c1.z, l1.w * c1.w);
            }
            B.u = lw[MODE < 2 ? cur : 0][c][j];
            float t = 0.f;
            #pragma unroll
            for (int r = 0; r < 4; ++r) t = fdot2f(A.h[r], B.h[r], t);
            if (c & 1) t2[c >> 1] = pk(tprev, t);
            else       tprev = t;
        }

        // ---- P over (c,n) ----
        float p[Ndim];
        #pragma unroll
        for (int n = 0; n < Ndim; ++n) p[n] = 0.f;
        #pragma unroll
        for (int cp8 = 0; cp8 < 8; ++cp8) {
            #pragma unroll
            for (int n = 0; n < Ndim; ++n)
                p[n] = fdot2f(t2[cp8], xa[cp8 * 8 + n], p[n]);
        }

        if (PASS == 0) {
            #pragma unroll
            for (int n = 0; n < Ndim; ++n) {
                float r = wave_sum63(p[n]);          // row sum on VALU (DPP)
                if (j == 63) {
                    size_t i0 = (size_t)(n * Odim + o) * Hdim + hh;
                    if (MODE == 0) rsp[(size_t)bw * S + i0] = r;
                    else atomicAdd(&rs[i0], r);
                }
                csl[iw][n][j] = p[n];
            }
            __syncthreads();   // csl ready (also drains this o's stage early — it had full compute to land)
            #pragma unroll
            for (int k = 0; k < 2; ++k) {
                int e = tid + k * 256;
                int n = e >> 6, jj = e & 63;
                float v = csl[0][n][jj] + csl[1][n][jj] + csl[2][n][jj] + csl[3][n][jj];
                size_t idx = (size_t)(n * Odim + o) * Hdim + w0 + jj;
                if (MODE == 0) csp[(size_t)bh * S + idx] = v;
                else atomicAdd(&cs[idx], v);
            }
        } else {
            float bb = biasg[o];
            #pragma unroll
            for (int n = 0; n < Ndim; ++n) {
                size_t i0 = (size_t)(n * Odim + o) * Hdim;
                float rv = rs[i0 + (size_t)ruh];     // uniform -> s_load
                float cv = cs[i0 + ww];              // coalesced, L2-hot
                float v = rv + cv - p[n] + bb;
                if (hh == ww) v = 0.f;
                outg[(i0 + hh) * Hdim + ww] = v;     // coalesced store
            }
        }
    }
}

__global__ __launch_bounds__(256)
void sylo_reduce(const float* __restrict__ rsp, const float* __restrict__ csp,
                 float* __restrict__ rs, float* __restrict__ cs)
{
    int t = blockIdx.x * 256 + threadIdx.x;   // < 131072
    const size_t S = (size_t)Ndim * Odim * Hdim;
    float a = 0.f;
    #pragma unroll
    for (int k = 0; k < NBW; ++k) a += rsp[(size_t)k * S + t];
    rs[t] = a;
    float b = 0.f;
    #pragma unroll 16
    for (int k = 0; k < NBH; ++k) b += csp[(size_t)k * S + t];
    cs[t] = b;
}

extern "C" void kernel_launch(void* const* d_in, const int* in_sizes, int n_in,
                              void* d_out, int out_size, void* d_ws, size_t ws_size,
                              hipStream_t stream)
{
    const float* X    = (const float*)d_in[0];
    const float* L    = (const float*)d_in[1];
    const float* bias = (const float*)d_in[2];
    const float* coup = (const float*)d_in[3];
    float* out = (float*)d_out;

    const size_t S    = (size_t)Ndim * Odim * Hdim;    // 131072
    const size_t NL16 = (size_t)Odim * Cdim * Hdim;    // 262144 rows of 16B
    const size_t need0 = NL16 * 16 * 2 + (NBW + NBH + 2) * S * 4;  // ~80 MB
    const size_t need1 = NL16 * 16 * 2 + 2 * S * 4;                // ~9.4 MB
    dim3 grid(NBW, NBH), blk(256);

    if (ws_size >= need0) {
        uint4* lsigT = (uint4*)d_ws;
        uint4* lraw  = lsigT + NL16;
        float* rsp = (float*)(lraw + NL16);
        float* csp = rsp + (size_t)NBW * S;
        float* rs  = csp + (size_t)NBH * S;
        float* cs  = rs + S;
        sylo_prep<<<dim3(1024), blk, 0, stream>>>(L, coup, lsigT, lraw);
        sylo_main<0,0><<<grid, blk, 0, stream>>>(X, L, coup, bias, lsigT, lraw, out, rsp, csp, rs, cs);
        sylo_reduce<<<dim3(512), blk, 0, stream>>>(rsp, csp, rs, cs);
        sylo_main<1,0><<<grid, blk, 0, stream>>>(X, L, coup, bias, lsigT, lraw, out, rsp, csp, rs, cs);
    } else if (ws_size >= need1) {
        uint4* lsigT = (uint4*)d_ws;
        uint4* lraw  = lsigT + NL16;
        float* rs = (float*)(lraw + NL16);
        float* cs = rs + S;
        hipMemsetAsync(rs, 0, 2 * S * sizeof(float), stream);
        sylo_prep<<<dim3(1024), blk, 0, stream>>>(L, coup, lsigT, lraw);
        sylo_main<0,1><<<grid, blk, 0, stream>>>(X, L, coup, bias, lsigT, lraw, out, nullptr, nullptr, rs, cs);
        sylo_main<1,1><<<grid, blk, 0, stream>>>(X, L, coup, bias, lsigT, lraw, out, nullptr, nullptr, rs, cs);
    } else {
        float* rs = (float*)d_ws;
        float* cs = rs + S;
        hipMemsetAsync(rs, 0, 2 * S * sizeof(float), stream);
        sylo_main<0,2><<<grid, blk, 0, stream>>>(X, L, coup, bias, nullptr, nullptr, out, nullptr, nullptr, rs, cs);
        sylo_main<1,2><<<grid, blk, 0, stream>>>(X, L, coup, bias, nullptr, nullptr, out, nullptr, nullptr, rs, cs);
    }
}